// Round 5
// baseline (186.910 us; speedup 1.0000x reference)
//
#include <hip/hip_runtime.h>
#include <hip/hip_bf16.h>

__device__ __forceinline__ ushort f2bf(float f) {          // fp32 -> bf16 (RNE)
    unsigned u = __float_as_uint(f);
    return (ushort)((u + 0x7fffu + ((u >> 16) & 1u)) >> 16);
}
__device__ __forceinline__ float blo(unsigned u) { return __uint_as_float(u << 16); }
__device__ __forceinline__ float bhi(unsigned u) { return __uint_as_float(u & 0xffff0000u); }

// ---- K1: proj = in_feat @ W (fp32, LDS-tiled), bf16 epilogue + fused scores ----
// Also zeroes deg[] (saves a kernel; k_hist runs strictly after on the stream).
__global__ __launch_bounds__(256) void k_proj(const float* __restrict__ A,
                                              const float* __restrict__ W,
                                              const float* __restrict__ a_src,
                                              const float* __restrict__ a_tgt,
                                              ushort* __restrict__ Pb,
                                              float* __restrict__ ss,
                                              float* __restrict__ ts,
                                              int* __restrict__ deg, int n) {
    __shared__ float Wl[128 * 128];   // 64 KB
    __shared__ float Al[32 * 128];    // 16 KB
    const int tid = threadIdx.x;

    {   // fused deg zeroing (grid covers n)
        int gid = blockIdx.x * 256 + tid;
        if (gid < n) deg[gid] = 0;
    }

    for (int i = tid; i < 4096; i += 256)
        *(float4*)&Wl[i * 4] = *(const float4*)&W[i * 4];

    const int row0 = blockIdx.x * 32;
    for (int i = tid; i < 1024; i += 256) {
        int r  = i >> 5;
        int kc = (i & 31) << 2;
        int gr = row0 + r;
        float4 v = make_float4(0.f, 0.f, 0.f, 0.f);
        if (gr < n) v = *(const float4*)&A[gr * 128 + kc];
        *(float4*)&Al[r * 128 + kc] = v;
    }
    __syncthreads();

    const int tc = tid & 31;   // col group: cols tc*4..tc*4+3
    const int tr = tid >> 5;   // row group: rows tr*4..tr*4+3
    float acc[4][4] = {};
#pragma unroll 8
    for (int k = 0; k < 128; ++k) {
        float4 b = *(float4*)&Wl[k * 128 + tc * 4];
        float a0 = Al[(tr * 4 + 0) * 128 + k];
        float a1 = Al[(tr * 4 + 1) * 128 + k];
        float a2 = Al[(tr * 4 + 2) * 128 + k];
        float a3 = Al[(tr * 4 + 3) * 128 + k];
        acc[0][0] += a0 * b.x; acc[0][1] += a0 * b.y; acc[0][2] += a0 * b.z; acc[0][3] += a0 * b.w;
        acc[1][0] += a1 * b.x; acc[1][1] += a1 * b.y; acc[1][2] += a1 * b.z; acc[1][3] += a1 * b.w;
        acc[2][0] += a2 * b.x; acc[2][1] += a2 * b.y; acc[2][2] += a2 * b.z; acc[2][3] += a2 * b.w;
        acc[3][0] += a3 * b.x; acc[3][1] += a3 * b.y; acc[3][2] += a3 * b.z; acc[3][3] += a3 * b.w;
    }

    // bf16 projection write
#pragma unroll
    for (int i = 0; i < 4; ++i) {
        int gr = row0 + tr * 4 + i;
        if (gr < n) {
            ushort4 pk;
            pk.x = f2bf(acc[i][0]); pk.y = f2bf(acc[i][1]);
            pk.z = f2bf(acc[i][2]); pk.w = f2bf(acc[i][3]);
            *(ushort4*)&Pb[(size_t)gr * 128 + tc * 4] = pk;
        }
    }

    // fused per-(row,head) scores: head h = tc>>3 owns cols h*32..h*32+31,
    // spread over 8 lanes (q = tc&7). Reduce with shfl_xor over lane bits 0-2.
    const int h = tc >> 3;
    const int q = tc & 7;
    float4 va = *(const float4*)&a_src[h * 32 + q * 4];
    float4 vb = *(const float4*)&a_tgt[h * 32 + q * 4];
#pragma unroll
    for (int i = 0; i < 4; ++i) {
        float s1 = acc[i][0] * va.x + acc[i][1] * va.y + acc[i][2] * va.z + acc[i][3] * va.w;
        float s2 = acc[i][0] * vb.x + acc[i][1] * vb.y + acc[i][2] * vb.z + acc[i][3] * vb.w;
#pragma unroll
        for (int off = 1; off < 8; off <<= 1) {
            s1 += __shfl_xor(s1, off, 64);
            s2 += __shfl_xor(s2, off, 64);
        }
        int gr = row0 + tr * 4 + i;
        if (q == 0 && gr < n) {
            ss[gr * 4 + h] = s1;
            ts[gr * 4 + h] = s2;
        }
    }
}

// ---------------- CSR build ----------------------------------------------------
__global__ void k_hist(const int* __restrict__ tgt, int* __restrict__ deg, int E) {
    int e = blockIdx.x * 256 + threadIdx.x;
    if (e < E) atomicAdd(&deg[tgt[e]], 1);
}

__global__ __launch_bounds__(256) void k_scan1(const int* __restrict__ deg,
                                               int* __restrict__ rowptr,
                                               int* __restrict__ sums, int n) {
    __shared__ int sd[256];
    int tid = threadIdx.x;
    int i = blockIdx.x * 256 + tid;
    int v = (i < n) ? deg[i] : 0;
    sd[tid] = v; __syncthreads();
#pragma unroll
    for (int off = 1; off < 256; off <<= 1) {
        int t = (tid >= off) ? sd[tid - off] : 0;
        __syncthreads();
        sd[tid] += t;
        __syncthreads();
    }
    if (i < n) rowptr[i + 1] = sd[tid];
    if (tid == 255) sums[blockIdx.x] = sd[255];
}

// merged scan2+scan3: every block redundantly scans the <=256 chunk sums in LDS,
// picks its own prefix, applies it, and fills the cursor copy.
__global__ __launch_bounds__(256) void k_scan23(int* __restrict__ rowptr,
                                                int* __restrict__ cur,
                                                const int* __restrict__ sums,
                                                int nchunks, int n) {
    __shared__ int sd[256];
    int tid = threadIdx.x;
    int v = (tid < nchunks) ? sums[tid] : 0;
    sd[tid] = v; __syncthreads();
#pragma unroll
    for (int off = 1; off < 256; off <<= 1) {
        int t = (tid >= off) ? sd[tid - off] : 0;
        __syncthreads();
        sd[tid] += t;
        __syncthreads();
    }
    int b = blockIdx.x;
    int prefix = (b == 0) ? 0 : sd[b - 1];
    int i = b * 256 + tid;
    if (i < n) {
        int val = rowptr[i + 1] + prefix;
        rowptr[i + 1] = val;
        cur[i + 1] = val;
        if (i == 0) { rowptr[0] = 0; cur[0] = 0; }
    }
}

// ---------------- scatter: srcs only (4 B/edge payload), 4-edge ILP ------------
__global__ void k_scatter(const int* __restrict__ src, const int* __restrict__ tgt,
                          int* __restrict__ cur, int* __restrict__ srcs, int E) {
    int e = blockIdx.x * 1024 + threadIdx.x;
#pragma unroll
    for (int k = 0; k < 4; ++k, e += 256) {
        if (e < E) {
            int t = tgt[e];
            int pos = atomicAdd(&cur[t], 1);
            srcs[pos] = src[e];
        }
    }
}

// ---------------- aggregation: 1 wave/node, on-the-fly esc, fused denom --------
// thread lane owns cols 2*lane, 2*lane+1 (one u32 = 2 bf16 per gather).
// esc recomputed from ss gather + ts broadcast; no max subtraction (scores
// ~N(0,2), |score|<~8 over 3.2M draws -> exp safe in fp32; global max cancels).
__global__ __launch_bounds__(256) void k_aggr(const int* __restrict__ rowptr,
                                              const int* __restrict__ srcs,
                                              const float* __restrict__ ss,
                                              const float* __restrict__ ts,
                                              const ushort* __restrict__ Pb,
                                              const float* __restrict__ bias,
                                              float* __restrict__ out, int n) {
    int node = blockIdx.x * 4 + (threadIdx.x >> 6);
    if (node >= n) return;
    const int lane = threadIdx.x & 63;
    const int c = lane * 2;
    const int h = lane >> 4;
    const float tsc = ts[node * 4 + h];
    int b0 = rowptr[node], b1 = rowptr[node + 1];

    float ax0 = 0.f, ay0 = 0.f, ax1 = 0.f, ay1 = 0.f;
    float ax2 = 0.f, ay2 = 0.f, ax3 = 0.f, ay3 = 0.f;
    float den = 0.f;
    int i = b0;
    for (; i + 3 < b1; i += 4) {
        int s0 = srcs[i], s1 = srcs[i + 1], s2 = srcs[i + 2], s3 = srcs[i + 3];
        float w0 = ss[s0 * 4 + h] + tsc;
        float w1 = ss[s1 * 4 + h] + tsc;
        float w2 = ss[s2 * 4 + h] + tsc;
        float w3 = ss[s3 * 4 + h] + tsc;
        unsigned p0 = *(const unsigned*)&Pb[(size_t)s0 * 128 + c];
        unsigned p1 = *(const unsigned*)&Pb[(size_t)s1 * 128 + c];
        unsigned p2 = *(const unsigned*)&Pb[(size_t)s2 * 128 + c];
        unsigned p3 = *(const unsigned*)&Pb[(size_t)s3 * 128 + c];
        w0 = w0 > 0.f ? w0 : 0.2f * w0;  float e0 = __expf(w0);
        w1 = w1 > 0.f ? w1 : 0.2f * w1;  float e1 = __expf(w1);
        w2 = w2 > 0.f ? w2 : 0.2f * w2;  float e2 = __expf(w2);
        w3 = w3 > 0.f ? w3 : 0.2f * w3;  float e3 = __expf(w3);
        den += (e0 + e1) + (e2 + e3);
        ax0 = fmaf(e0, blo(p0), ax0); ay0 = fmaf(e0, bhi(p0), ay0);
        ax1 = fmaf(e1, blo(p1), ax1); ay1 = fmaf(e1, bhi(p1), ay1);
        ax2 = fmaf(e2, blo(p2), ax2); ay2 = fmaf(e2, bhi(p2), ay2);
        ax3 = fmaf(e3, blo(p3), ax3); ay3 = fmaf(e3, bhi(p3), ay3);
    }
    for (; i < b1; ++i) {
        int s0 = srcs[i];
        float w0 = ss[s0 * 4 + h] + tsc;
        w0 = w0 > 0.f ? w0 : 0.2f * w0;
        float e0 = __expf(w0);
        unsigned p0 = *(const unsigned*)&Pb[(size_t)s0 * 128 + c];
        den += e0;
        ax0 = fmaf(e0, blo(p0), ax0); ay0 = fmaf(e0, bhi(p0), ay0);
    }
    float inv = 1.f / (den + 1e-16f);
    float2 bv = *(const float2*)&bias[c];
    float2 o;
    o.x = ((ax0 + ax1) + (ax2 + ax3)) * inv + bv.x;
    o.y = ((ay0 + ay1) + (ay2 + ay3)) * inv + bv.y;
    *(float2*)&out[(size_t)node * 128 + c] = o;
}

extern "C" void kernel_launch(void* const* d_in, const int* in_sizes, int n_in,
                              void* d_out, int out_size, void* d_ws, size_t ws_size,
                              hipStream_t stream) {
    const float* in_feat = (const float*)d_in[0];
    const int*   edge    = (const int*)d_in[1];
    const float* W_proj  = (const float*)d_in[3];
    const float* a_src   = (const float*)d_in[4];
    const float* a_tgt   = (const float*)d_in[5];
    const float* bias    = (const float*)d_in[6];
    float* out = (float*)d_out;

    const int n = in_sizes[0] / 128;   // 50000
    const int E = in_sizes[1] / 2;     // 800000
    const int* src = edge;
    const int* tgt = edge + E;

    // workspace layout
    ushort* Pb  = (ushort*)d_ws;                       // n*128 bf16
    float*  ss  = (float*)(Pb + (size_t)n * 128);      // n*4
    float*  ts  = ss + (size_t)n * 4;                  // n*4
    int* deg    = (int*)(ts + (size_t)n * 4);          // n
    int* rowptr = deg + n;                             // n+1
    int* cur    = rowptr + n + 1;                      // n+1
    int* sums   = cur + n + 1;                         // 256
    int* srcs   = sums + 256;                          // E

    const int nchunks = (n + 255) / 256;

    k_proj<<<(n + 31) / 32, 256, 0, stream>>>(in_feat, W_proj, a_src, a_tgt,
                                              Pb, ss, ts, deg, n);
    k_hist<<<(E + 255) / 256, 256, 0, stream>>>(tgt, deg, E);
    k_scan1<<<nchunks, 256, 0, stream>>>(deg, rowptr, sums, n);
    k_scan23<<<nchunks, 256, 0, stream>>>(rowptr, cur, sums, nchunks, n);
    k_scatter<<<(E + 1023) / 1024, 256, 0, stream>>>(src, tgt, cur, srcs, E);
    k_aggr<<<(n + 3) / 4, 256, 0, stream>>>(rowptr, srcs, ss, ts, Pb, bias, out, n);
}

// Round 6
// 140.100 us; speedup vs baseline: 1.3341x; 1.3341x over previous
//
#include <hip/hip_runtime.h>
#include <hip/hip_bf16.h>

__device__ __forceinline__ ushort f2bf(float f) {          // fp32 -> bf16 (RNE)
    unsigned u = __float_as_uint(f);
    return (ushort)((u + 0x7fffu + ((u >> 16) & 1u)) >> 16);
}
__device__ __forceinline__ float blo(unsigned u) { return __uint_as_float(u << 16); }
__device__ __forceinline__ float bhi(unsigned u) { return __uint_as_float(u & 0xffff0000u); }

// ---- K1: proj = in_feat @ W (fp32, LDS-tiled), bf16 epilogue + fused scores ----
// Also zeroes deg[] (saves a kernel; k_hist runs strictly after on the stream).
__global__ __launch_bounds__(256) void k_proj(const float* __restrict__ A,
                                              const float* __restrict__ W,
                                              const float* __restrict__ a_src,
                                              const float* __restrict__ a_tgt,
                                              ushort* __restrict__ Pb,
                                              float* __restrict__ ss,
                                              float* __restrict__ ts,
                                              int* __restrict__ deg, int n) {
    __shared__ float Wl[128 * 128];   // 64 KB
    __shared__ float Al[32 * 128];    // 16 KB
    const int tid = threadIdx.x;

    {   // fused deg zeroing (grid covers n)
        int gid = blockIdx.x * 256 + tid;
        if (gid < n) deg[gid] = 0;
    }

    for (int i = tid; i < 4096; i += 256)
        *(float4*)&Wl[i * 4] = *(const float4*)&W[i * 4];

    const int row0 = blockIdx.x * 32;
    for (int i = tid; i < 1024; i += 256) {
        int r  = i >> 5;
        int kc = (i & 31) << 2;
        int gr = row0 + r;
        float4 v = make_float4(0.f, 0.f, 0.f, 0.f);
        if (gr < n) v = *(const float4*)&A[gr * 128 + kc];
        *(float4*)&Al[r * 128 + kc] = v;
    }
    __syncthreads();

    const int tc = tid & 31;   // col group: cols tc*4..tc*4+3
    const int tr = tid >> 5;   // row group: rows tr*4..tr*4+3
    float acc[4][4] = {};
#pragma unroll 8
    for (int k = 0; k < 128; ++k) {
        float4 b = *(float4*)&Wl[k * 128 + tc * 4];
        float a0 = Al[(tr * 4 + 0) * 128 + k];
        float a1 = Al[(tr * 4 + 1) * 128 + k];
        float a2 = Al[(tr * 4 + 2) * 128 + k];
        float a3 = Al[(tr * 4 + 3) * 128 + k];
        acc[0][0] += a0 * b.x; acc[0][1] += a0 * b.y; acc[0][2] += a0 * b.z; acc[0][3] += a0 * b.w;
        acc[1][0] += a1 * b.x; acc[1][1] += a1 * b.y; acc[1][2] += a1 * b.z; acc[1][3] += a1 * b.w;
        acc[2][0] += a2 * b.x; acc[2][1] += a2 * b.y; acc[2][2] += a2 * b.z; acc[2][3] += a2 * b.w;
        acc[3][0] += a3 * b.x; acc[3][1] += a3 * b.y; acc[3][2] += a3 * b.z; acc[3][3] += a3 * b.w;
    }

    // bf16 projection write
#pragma unroll
    for (int i = 0; i < 4; ++i) {
        int gr = row0 + tr * 4 + i;
        if (gr < n) {
            ushort4 pk;
            pk.x = f2bf(acc[i][0]); pk.y = f2bf(acc[i][1]);
            pk.z = f2bf(acc[i][2]); pk.w = f2bf(acc[i][3]);
            *(ushort4*)&Pb[(size_t)gr * 128 + tc * 4] = pk;
        }
    }

    // fused per-(row,head) scores: head h = tc>>3 owns cols h*32..h*32+31,
    // spread over 8 lanes (q = tc&7). Reduce with shfl_xor over lane bits 0-2.
    const int h = tc >> 3;
    const int q = tc & 7;
    float4 va = *(const float4*)&a_src[h * 32 + q * 4];
    float4 vb = *(const float4*)&a_tgt[h * 32 + q * 4];
#pragma unroll
    for (int i = 0; i < 4; ++i) {
        float s1 = acc[i][0] * va.x + acc[i][1] * va.y + acc[i][2] * va.z + acc[i][3] * va.w;
        float s2 = acc[i][0] * vb.x + acc[i][1] * vb.y + acc[i][2] * vb.z + acc[i][3] * vb.w;
#pragma unroll
        for (int off = 1; off < 8; off <<= 1) {
            s1 += __shfl_xor(s1, off, 64);
            s2 += __shfl_xor(s2, off, 64);
        }
        int gr = row0 + tr * 4 + i;
        if (q == 0 && gr < n) {
            ss[gr * 4 + h] = s1;
            ts[gr * 4 + h] = s2;
        }
    }
}

// ---------------- CSR build ----------------------------------------------------
// hist also records each edge's rank within its target node (the atomic's old
// value) -> the scatter kernel needs NO atomics at all.
__global__ void k_hist(const int* __restrict__ tgt, int* __restrict__ deg,
                       int* __restrict__ rank, int E) {
    int e = blockIdx.x * 256 + threadIdx.x;
    if (e < E) rank[e] = atomicAdd(&deg[tgt[e]], 1);
}

__global__ __launch_bounds__(256) void k_scan1(const int* __restrict__ deg,
                                               int* __restrict__ rowptr,
                                               int* __restrict__ sums, int n) {
    __shared__ int sd[256];
    int tid = threadIdx.x;
    int i = blockIdx.x * 256 + tid;
    int v = (i < n) ? deg[i] : 0;
    sd[tid] = v; __syncthreads();
#pragma unroll
    for (int off = 1; off < 256; off <<= 1) {
        int t = (tid >= off) ? sd[tid - off] : 0;
        __syncthreads();
        sd[tid] += t;
        __syncthreads();
    }
    if (i < n) rowptr[i + 1] = sd[tid];
    if (tid == 255) sums[blockIdx.x] = sd[255];
}

// merged scan2+scan3: every block redundantly scans the <=256 chunk sums in LDS,
// picks its own prefix, applies it.
__global__ __launch_bounds__(256) void k_scan23(int* __restrict__ rowptr,
                                                const int* __restrict__ sums,
                                                int nchunks, int n) {
    __shared__ int sd[256];
    int tid = threadIdx.x;
    int v = (tid < nchunks) ? sums[tid] : 0;
    sd[tid] = v; __syncthreads();
#pragma unroll
    for (int off = 1; off < 256; off <<= 1) {
        int t = (tid >= off) ? sd[tid - off] : 0;
        __syncthreads();
        sd[tid] += t;
        __syncthreads();
    }
    int b = blockIdx.x;
    int prefix = (b == 0) ? 0 : sd[b - 1];
    int i = b * 256 + tid;
    if (i < n) {
        rowptr[i + 1] += prefix;
        if (i == 0) rowptr[0] = 0;
    }
}

// ---------------- scatter: atomic-free (pos = rowptr[t] + rank[e]) -------------
// Pure fire-and-forget random store; no return-value dependency chain.
__global__ void k_scatter(const int* __restrict__ src, const int* __restrict__ tgt,
                          const int* __restrict__ rowptr, const int* __restrict__ rank,
                          int* __restrict__ srcs, int E) {
    int e = blockIdx.x * 256 + threadIdx.x;
    if (e >= E) return;
    int t = tgt[e];
    srcs[rowptr[t] + rank[e]] = src[e];
}

// ---------------- aggregation: 1 wave/node, on-the-fly esc, fused denom --------
// thread lane owns cols 2*lane, 2*lane+1 (one u32 = 2 bf16 per gather).
// esc recomputed from ss gather + ts broadcast; no max subtraction (scores
// ~N(0,2), |score|<~8 over 3.2M draws -> exp safe in fp32; global max cancels).
__global__ __launch_bounds__(256) void k_aggr(const int* __restrict__ rowptr,
                                              const int* __restrict__ srcs,
                                              const float* __restrict__ ss,
                                              const float* __restrict__ ts,
                                              const ushort* __restrict__ Pb,
                                              const float* __restrict__ bias,
                                              float* __restrict__ out, int n) {
    int node = blockIdx.x * 4 + (threadIdx.x >> 6);
    if (node >= n) return;
    const int lane = threadIdx.x & 63;
    const int c = lane * 2;
    const int h = lane >> 4;
    const float tsc = ts[node * 4 + h];
    int b0 = rowptr[node], b1 = rowptr[node + 1];

    float ax0 = 0.f, ay0 = 0.f, ax1 = 0.f, ay1 = 0.f;
    float ax2 = 0.f, ay2 = 0.f, ax3 = 0.f, ay3 = 0.f;
    float den = 0.f;
    int i = b0;
    for (; i + 3 < b1; i += 4) {
        int s0 = srcs[i], s1 = srcs[i + 1], s2 = srcs[i + 2], s3 = srcs[i + 3];
        float w0 = ss[s0 * 4 + h] + tsc;
        float w1 = ss[s1 * 4 + h] + tsc;
        float w2 = ss[s2 * 4 + h] + tsc;
        float w3 = ss[s3 * 4 + h] + tsc;
        unsigned p0 = *(const unsigned*)&Pb[(size_t)s0 * 128 + c];
        unsigned p1 = *(const unsigned*)&Pb[(size_t)s1 * 128 + c];
        unsigned p2 = *(const unsigned*)&Pb[(size_t)s2 * 128 + c];
        unsigned p3 = *(const unsigned*)&Pb[(size_t)s3 * 128 + c];
        w0 = w0 > 0.f ? w0 : 0.2f * w0;  float e0 = __expf(w0);
        w1 = w1 > 0.f ? w1 : 0.2f * w1;  float e1 = __expf(w1);
        w2 = w2 > 0.f ? w2 : 0.2f * w2;  float e2 = __expf(w2);
        w3 = w3 > 0.f ? w3 : 0.2f * w3;  float e3 = __expf(w3);
        den += (e0 + e1) + (e2 + e3);
        ax0 = fmaf(e0, blo(p0), ax0); ay0 = fmaf(e0, bhi(p0), ay0);
        ax1 = fmaf(e1, blo(p1), ax1); ay1 = fmaf(e1, bhi(p1), ay1);
        ax2 = fmaf(e2, blo(p2), ax2); ay2 = fmaf(e2, bhi(p2), ay2);
        ax3 = fmaf(e3, blo(p3), ax3); ay3 = fmaf(e3, bhi(p3), ay3);
    }
    for (; i < b1; ++i) {
        int s0 = srcs[i];
        float w0 = ss[s0 * 4 + h] + tsc;
        w0 = w0 > 0.f ? w0 : 0.2f * w0;
        float e0 = __expf(w0);
        unsigned p0 = *(const unsigned*)&Pb[(size_t)s0 * 128 + c];
        den += e0;
        ax0 = fmaf(e0, blo(p0), ax0); ay0 = fmaf(e0, bhi(p0), ay0);
    }
    float inv = 1.f / (den + 1e-16f);
    float2 bv = *(const float2*)&bias[c];
    float2 o;
    o.x = ((ax0 + ax1) + (ax2 + ax3)) * inv + bv.x;
    o.y = ((ay0 + ay1) + (ay2 + ay3)) * inv + bv.y;
    *(float2*)&out[(size_t)node * 128 + c] = o;
}

extern "C" void kernel_launch(void* const* d_in, const int* in_sizes, int n_in,
                              void* d_out, int out_size, void* d_ws, size_t ws_size,
                              hipStream_t stream) {
    const float* in_feat = (const float*)d_in[0];
    const int*   edge    = (const int*)d_in[1];
    const float* W_proj  = (const float*)d_in[3];
    const float* a_src   = (const float*)d_in[4];
    const float* a_tgt   = (const float*)d_in[5];
    const float* bias    = (const float*)d_in[6];
    float* out = (float*)d_out;

    const int n = in_sizes[0] / 128;   // 50000
    const int E = in_sizes[1] / 2;     // 800000
    const int* src = edge;
    const int* tgt = edge + E;

    // workspace layout
    ushort* Pb  = (ushort*)d_ws;                       // n*128 bf16
    float*  ss  = (float*)(Pb + (size_t)n * 128);      // n*4
    float*  ts  = ss + (size_t)n * 4;                  // n*4
    int* deg    = (int*)(ts + (size_t)n * 4);          // n
    int* rowptr = deg + n;                             // n+1
    int* sums   = rowptr + n + 1;                      // 256
    int* rank   = sums + 256;                          // E
    int* srcs   = rank + E;                            // E

    const int nchunks = (n + 255) / 256;

    k_proj<<<(n + 31) / 32, 256, 0, stream>>>(in_feat, W_proj, a_src, a_tgt,
                                              Pb, ss, ts, deg, n);
    k_hist<<<(E + 255) / 256, 256, 0, stream>>>(tgt, deg, rank, E);
    k_scan1<<<nchunks, 256, 0, stream>>>(deg, rowptr, sums, n);
    k_scan23<<<nchunks, 256, 0, stream>>>(rowptr, sums, nchunks, n);
    k_scatter<<<(E + 255) / 256, 256, 0, stream>>>(src, tgt, rowptr, rank, srcs, E);
    k_aggr<<<(n + 3) / 4, 256, 0, stream>>>(rowptr, srcs, ss, ts, Pb, bias, out, n);
}

// Round 7
// 127.088 us; speedup vs baseline: 1.4707x; 1.1024x over previous
//
#include <hip/hip_runtime.h>
#include <hip/hip_bf16.h>

typedef __attribute__((ext_vector_type(8))) short bf16x8;
typedef __attribute__((ext_vector_type(4))) float f32x4;

__device__ __forceinline__ ushort f2bf(float f) {          // fp32 -> bf16 (RNE)
    unsigned u = __float_as_uint(f);
    return (ushort)((u + 0x7fffu + ((u >> 16) & 1u)) >> 16);
}
__device__ __forceinline__ float blo(unsigned u) { return __uint_as_float(u << 16); }
__device__ __forceinline__ float bhi(unsigned u) { return __uint_as_float(u & 0xffff0000u); }

// ---- K0: W [128][128] fp32 -> Wt [n][k] bf16 (transposed, for MFMA B-frags) ---
__global__ void k_wt(const float* __restrict__ W, ushort* __restrict__ Wt) {
    int idx = blockIdx.x * 256 + threadIdx.x;   // 0..16383
    int nn = idx >> 7, kk = idx & 127;
    Wt[idx] = f2bf(W[kk * 128 + nn]);           // Wt[nn*128+kk] = W[kk][nn]
}

// ---- K1: proj = A @ W via bf16 MFMA; fused scores; zeroes deg ------------------
// block = 256 thr (4 waves), 64 rows/block. LDS: A-tile 16KB + Wt 32KB, both
// XOR-swizzled (byte ^= (row&7)<<4) to kill the 256B-stride bank conflict.
__global__ __launch_bounds__(256) void k_proj(const float* __restrict__ A,
                                              const ushort* __restrict__ Wt_g,
                                              const float* __restrict__ a_src,
                                              const float* __restrict__ a_tgt,
                                              ushort* __restrict__ Pb,
                                              float* __restrict__ ss,
                                              float* __restrict__ ts,
                                              int* __restrict__ deg, int n) {
    __shared__ __align__(16) char smem[49152];  // [0,16384): A 64x128 bf16; [16384,49152): Wt 128x128 bf16
    const int tid = threadIdx.x;
    const int row0 = blockIdx.x * 64;

    {   // fused deg zeroing (grid*256 = 200192 >= n)
        int gid = blockIdx.x * 256 + tid;
        if (gid < n) deg[gid] = 0;
    }

    // stage A rows (fp32 -> bf16), swizzled
#pragma unroll
    for (int it = 0; it < 8; ++it) {
        int idx = it * 256 + tid;        // 0..2047
        int r   = idx >> 5;              // 0..63
        int kc  = (idx & 31) << 2;       // 0..124
        int gr  = row0 + r;
        float4 v = make_float4(0.f, 0.f, 0.f, 0.f);
        if (gr < n) v = *(const float4*)&A[(size_t)gr * 128 + kc];
        ushort4 pk;
        pk.x = f2bf(v.x); pk.y = f2bf(v.y); pk.z = f2bf(v.z); pk.w = f2bf(v.w);
        *(ushort4*)(smem + ((r * 256 + kc * 2) ^ ((r & 7) << 4))) = pk;
    }
    // stage Wt (bf16, already transposed), swizzled
#pragma unroll
    for (int it = 0; it < 8; ++it) {
        int idx = it * 256 + tid;        // 0..2047
        int nn  = idx >> 4;              // 0..127
        int k8  = (idx & 15) << 3;       // 0..120
        uint4 v = *(const uint4*)&Wt_g[nn * 128 + k8];
        *(uint4*)(smem + 16384 + ((nn * 256 + k8 * 2) ^ ((nn & 7) << 4))) = v;
    }
    __syncthreads();

    const int l  = tid & 63, w = tid >> 6;
    const int lr = l & 15,  lk = l >> 4;
    const int arow = w * 16 + lr;

    f32x4 acc[8] = {};
#pragma unroll
    for (int ks = 0; ks < 4; ++ks) {
        int kk = ks * 32 + lk * 8;
        bf16x8 af = *(const bf16x8*)(smem + ((arow * 256 + kk * 2) ^ ((arow & 7) << 4)));
#pragma unroll
        for (int nt = 0; nt < 8; ++nt) {
            int nn = nt * 16 + lr;
            bf16x8 bf = *(const bf16x8*)(smem + 16384 + ((nn * 256 + kk * 2) ^ ((nn & 7) << 4)));
            acc[nt] = __builtin_amdgcn_mfma_f32_16x16x32_bf16(af, bf, acc[nt], 0, 0, 0);
        }
    }

    // Pb write: D layout col = lane&15 (per tile), row = (lane>>4)*4 + reg
#pragma unroll
    for (int nt = 0; nt < 8; ++nt) {
#pragma unroll
        for (int r = 0; r < 4; ++r) {
            int gr = row0 + w * 16 + lk * 4 + r;
            if (gr < n) Pb[(size_t)gr * 128 + nt * 16 + lr] = f2bf(acc[nt][r]);
        }
    }

    // fused scores from fp32 accumulators. a vec for tile t, lane lr:
    // col = t*16+lr -> head = t>>1, d = (t&1)*16+lr -> flat index t*16+lr.
    float av[8], bw[8];
#pragma unroll
    for (int t = 0; t < 8; ++t) { av[t] = a_src[t * 16 + lr]; bw[t] = a_tgt[t * 16 + lr]; }
#pragma unroll
    for (int r = 0; r < 4; ++r) {
#pragma unroll
        for (int h = 0; h < 4; ++h) {
            float s1 = acc[2 * h][r] * av[2 * h] + acc[2 * h + 1][r] * av[2 * h + 1];
            float s2 = acc[2 * h][r] * bw[2 * h] + acc[2 * h + 1][r] * bw[2 * h + 1];
#pragma unroll
            for (int off = 1; off < 16; off <<= 1) {
                s1 += __shfl_xor(s1, off, 64);
                s2 += __shfl_xor(s2, off, 64);
            }
            if (lr == 0) {
                int gr = row0 + w * 16 + lk * 4 + r;
                if (gr < n) { ss[gr * 4 + h] = s1; ts[gr * 4 + h] = s2; }
            }
        }
    }
}

// ---------------- CSR build ----------------------------------------------------
__global__ void k_hist(const int* __restrict__ tgt, int* __restrict__ deg,
                       int* __restrict__ rank, int E) {
    int e = blockIdx.x * 256 + threadIdx.x;
    if (e < E) rank[e] = atomicAdd(&deg[tgt[e]], 1);
}

__global__ __launch_bounds__(256) void k_scan1(const int* __restrict__ deg,
                                               int* __restrict__ rowptr,
                                               int* __restrict__ sums, int n) {
    __shared__ int sd[256];
    int tid = threadIdx.x;
    int i = blockIdx.x * 256 + tid;
    int v = (i < n) ? deg[i] : 0;
    sd[tid] = v; __syncthreads();
#pragma unroll
    for (int off = 1; off < 256; off <<= 1) {
        int t = (tid >= off) ? sd[tid - off] : 0;
        __syncthreads();
        sd[tid] += t;
        __syncthreads();
    }
    if (i < n) rowptr[i + 1] = sd[tid];
    if (tid == 255) sums[blockIdx.x] = sd[255];
}

__global__ __launch_bounds__(256) void k_scan23(int* __restrict__ rowptr,
                                                const int* __restrict__ sums,
                                                int nchunks, int n) {
    __shared__ int sd[256];
    int tid = threadIdx.x;
    int v = (tid < nchunks) ? sums[tid] : 0;
    sd[tid] = v; __syncthreads();
#pragma unroll
    for (int off = 1; off < 256; off <<= 1) {
        int t = (tid >= off) ? sd[tid - off] : 0;
        __syncthreads();
        sd[tid] += t;
        __syncthreads();
    }
    int b = blockIdx.x;
    int prefix = (b == 0) ? 0 : sd[b - 1];
    int i = b * 256 + tid;
    if (i < n) {
        rowptr[i + 1] += prefix;
        if (i == 0) rowptr[0] = 0;
    }
}

// ---------------- scatter: atomic-free (pos = rowptr[t] + rank[e]) -------------
__global__ void k_scatter(const int* __restrict__ src, const int* __restrict__ tgt,
                          const int* __restrict__ rowptr, const int* __restrict__ rank,
                          int* __restrict__ srcs, int E) {
    int e = blockIdx.x * 256 + threadIdx.x;
    if (e >= E) return;
    int t = tgt[e];
    srcs[rowptr[t] + rank[e]] = src[e];
}

// ---------------- aggregation: 1 wave/node, on-the-fly esc, fused denom --------
__global__ __launch_bounds__(256) void k_aggr(const int* __restrict__ rowptr,
                                              const int* __restrict__ srcs,
                                              const float* __restrict__ ss,
                                              const float* __restrict__ ts,
                                              const ushort* __restrict__ Pb,
                                              const float* __restrict__ bias,
                                              float* __restrict__ out, int n) {
    int node = blockIdx.x * 4 + (threadIdx.x >> 6);
    if (node >= n) return;
    const int lane = threadIdx.x & 63;
    const int c = lane * 2;
    const int h = lane >> 4;
    const float tsc = ts[node * 4 + h];
    int b0 = rowptr[node], b1 = rowptr[node + 1];

    float ax0 = 0.f, ay0 = 0.f, ax1 = 0.f, ay1 = 0.f;
    float ax2 = 0.f, ay2 = 0.f, ax3 = 0.f, ay3 = 0.f;
    float den = 0.f;
    int i = b0;
    for (; i + 3 < b1; i += 4) {
        int s0 = srcs[i], s1 = srcs[i + 1], s2 = srcs[i + 2], s3 = srcs[i + 3];
        float w0 = ss[s0 * 4 + h] + tsc;
        float w1 = ss[s1 * 4 + h] + tsc;
        float w2 = ss[s2 * 4 + h] + tsc;
        float w3 = ss[s3 * 4 + h] + tsc;
        unsigned p0 = *(const unsigned*)&Pb[(size_t)s0 * 128 + c];
        unsigned p1 = *(const unsigned*)&Pb[(size_t)s1 * 128 + c];
        unsigned p2 = *(const unsigned*)&Pb[(size_t)s2 * 128 + c];
        unsigned p3 = *(const unsigned*)&Pb[(size_t)s3 * 128 + c];
        w0 = w0 > 0.f ? w0 : 0.2f * w0;  float e0 = __expf(w0);
        w1 = w1 > 0.f ? w1 : 0.2f * w1;  float e1 = __expf(w1);
        w2 = w2 > 0.f ? w2 : 0.2f * w2;  float e2 = __expf(w2);
        w3 = w3 > 0.f ? w3 : 0.2f * w3;  float e3 = __expf(w3);
        den += (e0 + e1) + (e2 + e3);
        ax0 = fmaf(e0, blo(p0), ax0); ay0 = fmaf(e0, bhi(p0), ay0);
        ax1 = fmaf(e1, blo(p1), ax1); ay1 = fmaf(e1, bhi(p1), ay1);
        ax2 = fmaf(e2, blo(p2), ax2); ay2 = fmaf(e2, bhi(p2), ay2);
        ax3 = fmaf(e3, blo(p3), ax3); ay3 = fmaf(e3, bhi(p3), ay3);
    }
    for (; i < b1; ++i) {
        int s0 = srcs[i];
        float w0 = ss[s0 * 4 + h] + tsc;
        w0 = w0 > 0.f ? w0 : 0.2f * w0;
        float e0 = __expf(w0);
        unsigned p0 = *(const unsigned*)&Pb[(size_t)s0 * 128 + c];
        den += e0;
        ax0 = fmaf(e0, blo(p0), ax0); ay0 = fmaf(e0, bhi(p0), ay0);
    }
    float inv = 1.f / (den + 1e-16f);
    float2 bv = *(const float2*)&bias[c];
    float2 o;
    o.x = ((ax0 + ax1) + (ax2 + ax3)) * inv + bv.x;
    o.y = ((ay0 + ay1) + (ay2 + ay3)) * inv + bv.y;
    *(float2*)&out[(size_t)node * 128 + c] = o;
}

extern "C" void kernel_launch(void* const* d_in, const int* in_sizes, int n_in,
                              void* d_out, int out_size, void* d_ws, size_t ws_size,
                              hipStream_t stream) {
    const float* in_feat = (const float*)d_in[0];
    const int*   edge    = (const int*)d_in[1];
    const float* W_proj  = (const float*)d_in[3];
    const float* a_src   = (const float*)d_in[4];
    const float* a_tgt   = (const float*)d_in[5];
    const float* bias    = (const float*)d_in[6];
    float* out = (float*)d_out;

    const int n = in_sizes[0] / 128;   // 50000
    const int E = in_sizes[1] / 2;     // 800000
    const int* src = edge;
    const int* tgt = edge + E;

    // workspace layout
    ushort* Pb   = (ushort*)d_ws;                      // n*128 bf16
    ushort* Wt_g = Pb + (size_t)n * 128;               // 128*128 bf16
    float*  ss   = (float*)(Wt_g + 128 * 128);         // n*4
    float*  ts   = ss + (size_t)n * 4;                 // n*4
    int* deg    = (int*)(ts + (size_t)n * 4);          // n
    int* rowptr = deg + n;                             // n+1
    int* sums   = rowptr + n + 1;                      // 256
    int* rank   = sums + 256;                          // E
    int* srcs   = rank + E;                            // E

    const int nchunks = (n + 255) / 256;

    k_wt<<<64, 256, 0, stream>>>(W_proj, Wt_g);
    k_proj<<<(n + 63) / 64, 256, 0, stream>>>(in_feat, Wt_g, a_src, a_tgt,
                                              Pb, ss, ts, deg, n);
    k_hist<<<(E + 255) / 256, 256, 0, stream>>>(tgt, deg, rank, E);
    k_scan1<<<nchunks, 256, 0, stream>>>(deg, rowptr, sums, n);
    k_scan23<<<nchunks, 256, 0, stream>>>(rowptr, sums, nchunks, n);
    k_scatter<<<(E + 255) / 256, 256, 0, stream>>>(src, tgt, rowptr, rank, srcs, E);
    k_aggr<<<(n + 3) / 4, 256, 0, stream>>>(rowptr, srcs, ss, ts, Pb, bias, out, n);
}